// Round 6
// baseline (186.263 us; speedup 1.0000x reference)
//
#include <hip/hip_runtime.h>
#include <hip/hip_bf16.h>
#include <math.h>

typedef unsigned short u16;
typedef __attribute__((ext_vector_type(8))) short short8;   // 8 bf16 (4 VGPRs)
typedef __attribute__((ext_vector_type(4))) float f32x4;

#define NB 8192
#define ND 64
// dist scale: S = exp(-dist/0.05) = exp2(-K*dist), K = 20/ln2
// We carry K^2 inside d2 so that S = exp2(-sqrt(K2*d2)).
#define K2     832.5475634f      // (20/ln2)^2
#define M2K2  -1665.0951268f     // -2*K2
#define LN2    0.69314718055994531f

#define GRID_X 128
#define GRID_Y 32
#define TOTAL_BLOCKS (GRID_X * GRID_Y)

// S from pre-scaled squared distance (d2K = K2 * dist^2)
__device__ __forceinline__ float simval2(float d2K) {
    return __builtin_amdgcn_exp2f(-__builtin_amdgcn_sqrtf(fmaxf(d2K, 0.0f)));
}

// ---------------- prep: bf16 convert, K2-scaled norms, diagS, zero accums ---
__global__ __launch_bounds__(256) void snn_prep(
    const float* __restrict__ text, const float* __restrict__ image,
    u16* __restrict__ textBf, u16* __restrict__ imageBf,
    float* __restrict__ normT, float* __restrict__ normI,
    float* __restrict__ diagS, float* __restrict__ sameSum,
    float* __restrict__ totSum, unsigned int* __restrict__ doneCnt,
    float* __restrict__ out)
{
    const int lane = threadIdx.x & 63;
    const int row  = blockIdx.x * 4 + (threadIdx.x >> 6);
    const int idx  = row * ND + lane;

    float t  = text[idx];
    float im = image[idx];
    __hip_bfloat16 tb = __float2bfloat16(t);
    __hip_bfloat16 ib = __float2bfloat16(im);
    u16 tbits, ibits;
    __builtin_memcpy(&tbits, &tb, 2);
    __builtin_memcpy(&ibits, &ib, 2);
    textBf[idx]  = tbits;
    imageBf[idx] = ibits;

    float nt = t * t;
    float ni = im * im;
    float dp = __bfloat162float(tb) * __bfloat162float(ib); // match MFMA path
    #pragma unroll
    for (int m = 32; m >= 1; m >>= 1) {
        nt += __shfl_xor(nt, m, 64);
        ni += __shfl_xor(ni, m, 64);
        dp += __shfl_xor(dp, m, 64);
    }
    if (lane == 0) {
        float snt = K2 * nt;
        float sni = K2 * ni;
        normT[row] = snt;
        normI[row] = sni;
        float d2K = fmaf(M2K2, dp, sni + snt);  // K2 * dist(image_r, text_r)^2
        diagS[row] = simval2(d2K);
        sameSum[row] = 0.0f;
        totSum[row]  = 0.0f;
        if (row == 0) { *doneCnt = 0u; out[0] = 0.0f; }
    }
}

// ---------------- main: fused pairwise S + grouped row sums + finalize ------
// Grid: (128 row-tiles, 32 col-chunks) = 4096 blocks. Block: 256 thr = 4 waves.
// Block tile: 64 rows x 256 cols. Wave: 16 rows x 256 cols (16 n-tiles of 16).
// Per-column transient accumulator keeps VGPR low (target 6-7 waves/SIMD;
// R4's acc[2][8] batch pinned VGPR=104 -> 4 waves/SIMD, 39% VALUBusy).
// NOTE: gfx950 unified VGPR/AGPR file — never force min-waves caps that would
// squeeze the live set (R1: min-waves=4 spilled 365 MB of scratch traffic).
__global__ __launch_bounds__(256, 2) void snn_main(
    const u16* __restrict__ textBf, const u16* __restrict__ imageBf,
    const float* __restrict__ normT, const float* __restrict__ normI,
    const int* __restrict__ groups, const float* __restrict__ diagS,
    float* __restrict__ sameSum, float* __restrict__ totSum,
    unsigned int* __restrict__ doneCnt, float* __restrict__ out)
{
    const int lane = threadIdx.x & 63;
    const int w    = threadIdx.x >> 6;
    const int g    = lane >> 4;      // 16-lane group id (0..3)
    const int l15  = lane & 15;
    const int rowBase  = blockIdx.x * 64 + w * 16;
    const int colChunk = blockIdx.y * 256;

    // A fragments (image rows 16), resident for the whole wave
    short8 aFrag0 = *(const short8*)(imageBf + (rowBase + l15) * ND + g * 8);
    short8 aFrag1 = *(const short8*)(imageBf + (rowBase + l15) * ND + 32 + g * 8);

    // per-thread row metadata: row(r) = rowBase + g*4 + r  (C layout 16x16)
    float nI[4];
    int   gI[4];
    #pragma unroll
    for (int r = 0; r < 4; ++r) {
        int row = rowBase + g * 4 + r;
        nI[r] = normI[row];
        gI[r] = groups[row];
    }

    float sameAcc[4] = {0.f, 0.f, 0.f, 0.f};
    float totAcc[4]  = {0.f, 0.f, 0.f, 0.f};

    #pragma unroll 2
    for (int n = 0; n < 16; ++n) {
        const int col = colChunk + n * 16 + l15;
        float nT = normT[col];
        int   gJ = groups[col];
        short8 b0 = *(const short8*)(textBf + col * ND + g * 8);
        short8 b1 = *(const short8*)(textBf + col * ND + 32 + g * 8);
        f32x4 acc = {0.f, 0.f, 0.f, 0.f};
        acc = __builtin_amdgcn_mfma_f32_16x16x32_bf16(aFrag0, b0, acc, 0, 0, 0);
        acc = __builtin_amdgcn_mfma_f32_16x16x32_bf16(aFrag1, b1, acc, 0, 0, 0);
        #pragma unroll
        for (int r = 0; r < 4; ++r) {
            float d2K = fmaf(M2K2, acc[r], nI[r] + nT);
            float s   = simval2(d2K);
            totAcc[r] += s;
            sameAcc[r] += (gI[r] == gJ) ? s : 0.0f;
        }
    }

    // reduce across the 16 lanes sharing each row, then one atomic per row
    #pragma unroll
    for (int r = 0; r < 4; ++r) {
        float sv = sameAcc[r];
        float tv = totAcc[r];
        #pragma unroll
        for (int mk = 8; mk >= 1; mk >>= 1) {
            sv += __shfl_xor(sv, mk, 64);
            tv += __shfl_xor(tv, mk, 64);
        }
        if (l15 == 0) {
            int row = rowBase + g * 4 + r;
            atomicAdd(&sameSum[row], sv);
            atomicAdd(&totSum[row], tv);
        }
    }

    // ---- fused finalize: last block to finish computes the scalar loss ----
    __shared__ int lastFlag;
    __shared__ float wsum[4];
    __syncthreads();                       // all waves' atomics issued
    if (threadIdx.x == 0) {
        __threadfence();                   // release: our atomics visible
        unsigned int old = atomicAdd(doneCnt, 1u);
        lastFlag = (old == TOTAL_BLOCKS - 1) ? 1 : 0;
    }
    __syncthreads();
    if (lastFlag) {
        __threadfence();                   // acquire side
        float partial = 0.0f;
        const int g0 = groups[0];
        for (int i = threadIdx.x; i < NB; i += 256) {
            float sameS = __hip_atomic_load(&sameSum[i], __ATOMIC_RELAXED,
                                            __HIP_MEMORY_SCOPE_AGENT);
            float tot   = __hip_atomic_load(&totSum[i], __ATOMIC_RELAXED,
                                            __HIP_MEMORY_SCOPE_AGENT);
            float diag  = diagS[i];
            float A = sameS - diag;            // same-group sum, j != i
            bool cond = (groups[i] == g0) && (i != 0);
            float num = cond ? A : (A + sameS);   // F == sameS
            float den = tot - sameS;
            bool valid = (num != 0.0f) && (den != 0.0f);
            float ratio = (valid ? num : 1.0f) / (valid ? den : 1.0f);
            partial += valid ? (-LN2 * __builtin_amdgcn_logf(ratio)) : 0.0f;
        }
        #pragma unroll
        for (int mk = 32; mk >= 1; mk >>= 1) partial += __shfl_xor(partial, mk, 64);
        if ((threadIdx.x & 63) == 0) wsum[threadIdx.x >> 6] = partial;
        __syncthreads();
        if (threadIdx.x == 0)
            out[0] = (wsum[0] + wsum[1] + wsum[2] + wsum[3]) * (1.0f / 8192.0f);
    }
}

// ---------------- launch ----------------------------------------------------
extern "C" void kernel_launch(void* const* d_in, const int* in_sizes, int n_in,
                              void* d_out, int out_size, void* d_ws, size_t ws_size,
                              hipStream_t stream) {
    const float* text  = (const float*)d_in[0];
    const float* image = (const float*)d_in[1];
    const int*   groups = (const int*)d_in[2];
    float* out = (float*)d_out;

    char* ws = (char*)d_ws;
    u16* textBf  = (u16*)ws;                          // 1 MB
    u16* imageBf = (u16*)(ws + (1 << 20));            // 1 MB
    float* normT   = (float*)(ws + (2 << 20));        // 32 KB each
    float* normI   = normT + NB;
    float* diagS   = normI + NB;
    float* sameSum = diagS + NB;
    float* totSum  = sameSum + NB;
    unsigned int* doneCnt = (unsigned int*)(totSum + NB);

    snn_prep<<<NB / 4, 256, 0, stream>>>(text, image, textBf, imageBf,
                                         normT, normI, diagS, sameSum, totSum,
                                         doneCnt, out);
    snn_main<<<dim3(GRID_X, GRID_Y), 256, 0, stream>>>(
        textBf, imageBf, normT, normI, groups, diagS,
        sameSum, totSum, doneCnt, out);
}

// Round 7
// 130.400 us; speedup vs baseline: 1.4284x; 1.4284x over previous
//
#include <hip/hip_runtime.h>
#include <hip/hip_bf16.h>
#include <math.h>

typedef unsigned short u16;
typedef __attribute__((ext_vector_type(8))) short short8;   // 8 bf16 (4 VGPRs)
typedef __attribute__((ext_vector_type(4))) float f32x4;

#define NB 8192
#define ND 64
// dist scale: S = exp(-dist/0.05) = exp2(-K*dist), K = 20/ln2
// We carry K^2 inside d2 so that S = exp2(-sqrt(K2*d2)).
#define K2     832.5475634f      // (20/ln2)^2
#define M2K2  -1665.0951268f     // -2*K2
#define LN2    0.69314718055994531f

#define GRID_X 64
#define GRID_Y 32
#define TOTAL_BLOCKS (GRID_X * GRID_Y)

// S from pre-scaled squared distance (d2K = K2 * dist^2)
__device__ __forceinline__ float simval2(float d2K) {
    return __builtin_amdgcn_exp2f(-__builtin_amdgcn_sqrtf(fmaxf(d2K, 0.0f)));
}

// ---------------- prep: bf16 convert, K2-scaled norms, diagS, zero accums ---
__global__ __launch_bounds__(256) void snn_prep(
    const float* __restrict__ text, const float* __restrict__ image,
    u16* __restrict__ textBf, u16* __restrict__ imageBf,
    float* __restrict__ normT, float* __restrict__ normI,
    float* __restrict__ diagS, float* __restrict__ sameSum,
    float* __restrict__ totSum, unsigned int* __restrict__ doneCnt,
    float* __restrict__ out)
{
    const int lane = threadIdx.x & 63;
    const int row  = blockIdx.x * 4 + (threadIdx.x >> 6);
    const int idx  = row * ND + lane;

    float t  = text[idx];
    float im = image[idx];
    __hip_bfloat16 tb = __float2bfloat16(t);
    __hip_bfloat16 ib = __float2bfloat16(im);
    u16 tbits, ibits;
    __builtin_memcpy(&tbits, &tb, 2);
    __builtin_memcpy(&ibits, &ib, 2);
    textBf[idx]  = tbits;
    imageBf[idx] = ibits;

    float nt = t * t;
    float ni = im * im;
    float dp = __bfloat162float(tb) * __bfloat162float(ib); // match MFMA path
    #pragma unroll
    for (int m = 32; m >= 1; m >>= 1) {
        nt += __shfl_xor(nt, m, 64);
        ni += __shfl_xor(ni, m, 64);
        dp += __shfl_xor(dp, m, 64);
    }
    if (lane == 0) {
        float snt = K2 * nt;
        float sni = K2 * ni;
        normT[row] = snt;
        normI[row] = sni;
        float d2K = fmaf(M2K2, dp, sni + snt);  // K2 * dist(image_r, text_r)^2
        diagS[row] = simval2(d2K);
        sameSum[row] = 0.0f;
        totSum[row]  = 0.0f;
        if (row == 0) { *doneCnt = 0u; out[0] = 0.0f; }
    }
}

// ---------------- main: LDS-staged pairwise S + grouped row sums + finalize -
// Grid: (64 row-tiles, 32 col-chunks) = 2048 blocks. Block: 256 thr = 4 waves.
// Block tile: 128 rows x 256 cols. Wave: 32 rows, acc[2][8] batch (R4-proven:
// the batch IS the memory ILP — R5's per-column transient collapsed to VGPR=32
// with zero outstanding loads and ran 2.5x slower; don't shrink it).
// All 4 waves read the same 256 B-columns -> stage once in LDS (32 KB),
// seg-XOR swizzled (seg ^= c&7; same involution on write & read) so the
// 16-lane column reads of ds_read_b128 spread across all banks.
// NOTE: gfx950 unified VGPR/AGPR file — never force min-waves caps that would
// squeeze the live set (R1: min-waves=4 spilled 365 MB of scratch traffic).
__global__ __launch_bounds__(256, 2) void snn_main(
    const u16* __restrict__ textBf, const u16* __restrict__ imageBf,
    const float* __restrict__ normT, const float* __restrict__ normI,
    const int* __restrict__ groups, const float* __restrict__ diagS,
    float* __restrict__ sameSum, float* __restrict__ totSum,
    unsigned int* __restrict__ doneCnt, float* __restrict__ out)
{
    __shared__ u16   Btile[256 * ND];   // 32 KB, seg-swizzled text columns
    __shared__ float NTs[256];          // K2-scaled col norms
    __shared__ int   GJs[256];          // col groups

    const int tid  = threadIdx.x;
    const int lane = tid & 63;
    const int w    = tid >> 6;
    const int g    = lane >> 4;      // 16-lane group id (0..3)
    const int l15  = lane & 15;
    const int rowBase  = blockIdx.x * 128 + w * 32;
    const int colChunk = blockIdx.y * 256;

    // ---- stage the 256-col B chunk into LDS (once per block) ----
    {
        const int cb = tid >> 3;     // 0..31
        const int s  = tid & 7;      // 16B segment within a column
        #pragma unroll
        for (int r = 0; r < 8; ++r) {
            int c = r * 32 + cb;
            short8 v = *(const short8*)(textBf + (colChunk + c) * ND + s * 8);
            *(short8*)&Btile[c * ND + ((s ^ (c & 7)) * 8)] = v;   // swizzled
        }
        NTs[tid] = normT[colChunk + tid];
        GJs[tid] = groups[colChunk + tid];
    }

    // A fragments + row metadata: global loads issued BEFORE the barrier so
    // they overlap the staging latency.
    short8 aFrag[2][2];
    #pragma unroll
    for (int m = 0; m < 2; ++m)
        #pragma unroll
        for (int kk = 0; kk < 2; ++kk)
            aFrag[m][kk] = *(const short8*)(imageBf +
                (rowBase + m * 16 + l15) * ND + kk * 32 + g * 8);

    float nI[2][4];
    int   gI[2][4];
    #pragma unroll
    for (int m = 0; m < 2; ++m)
        #pragma unroll
        for (int r = 0; r < 4; ++r) {
            int row = rowBase + m * 16 + g * 4 + r;
            nI[m][r] = normI[row];
            gI[m][r] = groups[row];
        }

    __syncthreads();

    float sameAcc[2][4];
    float totAcc[2][4];
    #pragma unroll
    for (int m = 0; m < 2; ++m)
        #pragma unroll
        for (int r = 0; r < 4; ++r) { sameAcc[m][r] = 0.0f; totAcc[m][r] = 0.0f; }

    #pragma unroll
    for (int ct = 0; ct < 2; ++ct) {
        float nT[8];
        int   gJ[8];
        f32x4 acc[2][8];
        #pragma unroll
        for (int n = 0; n < 8; ++n) {
            const int c = ct * 128 + n * 16 + l15;     // col within chunk
            nT[n] = NTs[c];
            gJ[n] = GJs[c];
            short8 b0 = *(const short8*)&Btile[c * ND + ((g       ^ (c & 7)) * 8)];
            short8 b1 = *(const short8*)&Btile[c * ND + (((4 + g) ^ (c & 7)) * 8)];
            #pragma unroll
            for (int m = 0; m < 2; ++m) {
                acc[m][n] = f32x4{0.f, 0.f, 0.f, 0.f};
                acc[m][n] = __builtin_amdgcn_mfma_f32_16x16x32_bf16(
                                aFrag[m][0], b0, acc[m][n], 0, 0, 0);
                acc[m][n] = __builtin_amdgcn_mfma_f32_16x16x32_bf16(
                                aFrag[m][1], b1, acc[m][n], 0, 0, 0);
            }
        }

        // epilogue: d2K -> S -> predicated row accumulation
        #pragma unroll
        for (int m = 0; m < 2; ++m)
            #pragma unroll
            for (int n = 0; n < 8; ++n) {
                f32x4 c = acc[m][n];
                #pragma unroll
                for (int r = 0; r < 4; ++r) {
                    float d2K = fmaf(M2K2, c[r], nI[m][r] + nT[n]);
                    float s   = simval2(d2K);
                    totAcc[m][r] += s;
                    sameAcc[m][r] += (gI[m][r] == gJ[n]) ? s : 0.0f;
                }
            }
    }

    // reduce across the 16 lanes sharing each row, then one atomic per row
    #pragma unroll
    for (int m = 0; m < 2; ++m)
        #pragma unroll
        for (int r = 0; r < 4; ++r) {
            float sv = sameAcc[m][r];
            float tv = totAcc[m][r];
            #pragma unroll
            for (int mk = 8; mk >= 1; mk >>= 1) {
                sv += __shfl_xor(sv, mk, 64);
                tv += __shfl_xor(tv, mk, 64);
            }
            if (l15 == 0) {
                int row = rowBase + m * 16 + g * 4 + r;
                atomicAdd(&sameSum[row], sv);
                atomicAdd(&totSum[row], tv);
            }
        }

    // ---- fused finalize: last block to finish computes the scalar loss ----
    __shared__ int lastFlag;
    __shared__ float wsum[4];
    __syncthreads();                       // all waves' atomics issued
    if (threadIdx.x == 0) {
        __threadfence();                   // release: our atomics visible
        unsigned int old = atomicAdd(doneCnt, 1u);
        lastFlag = (old == TOTAL_BLOCKS - 1) ? 1 : 0;
    }
    __syncthreads();
    if (lastFlag) {
        __threadfence();                   // acquire side
        float partial = 0.0f;
        const int g0 = groups[0];
        for (int i = threadIdx.x; i < NB; i += 256) {
            float sameS = __hip_atomic_load(&sameSum[i], __ATOMIC_RELAXED,
                                            __HIP_MEMORY_SCOPE_AGENT);
            float tot   = __hip_atomic_load(&totSum[i], __ATOMIC_RELAXED,
                                            __HIP_MEMORY_SCOPE_AGENT);
            float diag  = diagS[i];
            float A = sameS - diag;            // same-group sum, j != i
            bool cond = (groups[i] == g0) && (i != 0);
            float num = cond ? A : (A + sameS);   // F == sameS
            float den = tot - sameS;
            bool valid = (num != 0.0f) && (den != 0.0f);
            float ratio = (valid ? num : 1.0f) / (valid ? den : 1.0f);
            partial += valid ? (-LN2 * __builtin_amdgcn_logf(ratio)) : 0.0f;
        }
        #pragma unroll
        for (int mk = 32; mk >= 1; mk >>= 1) partial += __shfl_xor(partial, mk, 64);
        if ((threadIdx.x & 63) == 0) wsum[threadIdx.x >> 6] = partial;
        __syncthreads();
        if (threadIdx.x == 0)
            out[0] = (wsum[0] + wsum[1] + wsum[2] + wsum[3]) * (1.0f / 8192.0f);
    }
}

// ---------------- launch ----------------------------------------------------
extern "C" void kernel_launch(void* const* d_in, const int* in_sizes, int n_in,
                              void* d_out, int out_size, void* d_ws, size_t ws_size,
                              hipStream_t stream) {
    const float* text  = (const float*)d_in[0];
    const float* image = (const float*)d_in[1];
    const int*   groups = (const int*)d_in[2];
    float* out = (float*)d_out;

    char* ws = (char*)d_ws;
    u16* textBf  = (u16*)ws;                          // 1 MB
    u16* imageBf = (u16*)(ws + (1 << 20));            // 1 MB
    float* normT   = (float*)(ws + (2 << 20));        // 32 KB each
    float* normI   = normT + NB;
    float* diagS   = normI + NB;
    float* sameSum = diagS + NB;
    float* totSum  = sameSum + NB;
    unsigned int* doneCnt = (unsigned int*)(totSum + NB);

    snn_prep<<<NB / 4, 256, 0, stream>>>(text, image, textBf, imageBf,
                                         normT, normI, diagS, sameSum, totSum,
                                         doneCnt, out);
    snn_main<<<dim3(GRID_X, GRID_Y), 256, 0, stream>>>(
        textBf, imageBf, normT, normI, groups, diagS,
        sameSum, totSum, doneCnt, out);
}